// Round 4
// baseline (525.754 us; speedup 1.0000x reference)
//
#include <hip/hip_runtime.h>

typedef __attribute__((ext_vector_type(4))) float f32x4;
typedef __attribute__((ext_vector_type(8))) short bf16x8;
typedef unsigned short u16;

constexpr int kB = 2, kS = 2048, kD = 1024, kH = 16, kHD = 64, kHID = 3584;
constexpr int kN = kB * kS;  // 4096 tokens

__device__ __forceinline__ u16 f2bf(float f) {
  unsigned u = __float_as_uint(f);
  u = (u + 0x7FFFu + ((u >> 16) & 1u)) >> 16;
  return (u16)u;
}
__device__ __forceinline__ float bf2f(u16 v) {
  return __uint_as_float((unsigned)v << 16);
}

// 16-lane (DPP row) max reduction: row_ror 1,2,4,8 + fmax. VALU latency, no LDS.
__device__ __forceinline__ float rowmax16(float v) {
  int t;
  t = __builtin_amdgcn_update_dpp(0, __float_as_int(v), 0x121, 0xf, 0xf, true);
  v = fmaxf(v, __int_as_float(t));
  t = __builtin_amdgcn_update_dpp(0, __float_as_int(v), 0x122, 0xf, 0xf, true);
  v = fmaxf(v, __int_as_float(t));
  t = __builtin_amdgcn_update_dpp(0, __float_as_int(v), 0x124, 0xf, 0xf, true);
  v = fmaxf(v, __int_as_float(t));
  t = __builtin_amdgcn_update_dpp(0, __float_as_int(v), 0x128, 0xf, 0xf, true);
  v = fmaxf(v, __int_as_float(t));
  return v;
}

#define AS1(p) ((const __attribute__((address_space(1))) void*)(p))
#define AS3(p) ((__attribute__((address_space(3))) void*)(p))

// ---------------------------------------------------------------- prep: x+pos, RMSNorm1
__global__ __launch_bounds__(256) void k_prep(
    const float* __restrict__ x, const float* __restrict__ pos,
    const float* __restrict__ w, float* __restrict__ xr, u16* __restrict__ xn) {
  const int n = blockIdx.x, t = threadIdx.x, s = n & (kS - 1);
  float4 a = ((const float4*)(x + (size_t)n * kD))[t];
  float4 p = ((const float4*)(pos + (size_t)s * kD))[t];
  a.x += p.x; a.y += p.y; a.z += p.z; a.w += p.w;
  ((float4*)(xr + (size_t)n * kD))[t] = a;
  float ss = a.x*a.x + a.y*a.y + a.z*a.z + a.w*a.w;
#pragma unroll
  for (int off = 1; off < 64; off <<= 1) ss += __shfl_xor(ss, off);
  __shared__ float red[4];
  if ((t & 63) == 0) red[t >> 6] = ss;
  __syncthreads();
  float rs = rsqrtf((red[0] + red[1] + red[2] + red[3]) * (1.0f / kD) + 1e-6f);
  float4 wv = ((const float4*)w)[t];
  ushort4 o;
  o.x = f2bf(a.x * rs * wv.x); o.y = f2bf(a.y * rs * wv.y);
  o.z = f2bf(a.z * rs * wv.z); o.w = f2bf(a.w * rs * wv.w);
  ((ushort4*)(xn + (size_t)n * kD))[t] = o;
}

// ---------------------------------------------------------------- RMSNorm2
__global__ __launch_bounds__(256) void k_rms2(
    const float* __restrict__ xin, const float* __restrict__ w, u16* __restrict__ xn) {
  const int n = blockIdx.x, t = threadIdx.x;
  float4 a = ((const float4*)(xin + (size_t)n * kD))[t];
  float ss = a.x*a.x + a.y*a.y + a.z*a.z + a.w*a.w;
#pragma unroll
  for (int off = 1; off < 64; off <<= 1) ss += __shfl_xor(ss, off);
  __shared__ float red[4];
  if ((t & 63) == 0) red[t >> 6] = ss;
  __syncthreads();
  float rs = rsqrtf((red[0] + red[1] + red[2] + red[3]) * (1.0f / kD) + 1e-6f);
  float4 wv = ((const float4*)w)[t];
  ushort4 o;
  o.x = f2bf(a.x * rs * wv.x); o.y = f2bf(a.y * rs * wv.y);
  o.z = f2bf(a.z * rs * wv.z); o.w = f2bf(a.w * rs * wv.w);
  ((ushort4*)(xn + (size_t)n * kD))[t] = o;
}

// ---------------------------------------------------------------- fused weight prep
__device__ __forceinline__ void cvt4(const float* __restrict__ s, u16* __restrict__ d, int j) {
  float4 v = ((const float4*)s)[j];
  ushort4 o;
  o.x = f2bf(v.x); o.y = f2bf(v.y); o.z = f2bf(v.z); o.w = f2bf(v.w);
  ((ushort4*)d)[j] = o;
}

__global__ __launch_bounds__(256) void k_wprep(
    const float* __restrict__ q_w, const float* __restrict__ k_w,
    const float* __restrict__ v_w, const float* __restrict__ o_w,
    const float* __restrict__ in_w, const float* __restrict__ gate_w,
    const float* __restrict__ out_w,
    const float* __restrict__ q_b, const float* __restrict__ k_b,
    const float* __restrict__ v_b,
    u16* __restrict__ W, float* __restrict__ bqkv) {
  const int i = blockIdx.x * 256 + threadIdx.x;
  if (i < 262144)       cvt4(q_w,    W + 0,        i);
  else if (i < 524288)  cvt4(k_w,    W + 1048576,  i - 262144);
  else if (i < 786432)  cvt4(v_w,    W + 2097152,  i - 524288);
  else if (i < 1048576) cvt4(o_w,    W + 3145728,  i - 786432);
  else if (i < 1966080) cvt4(in_w,   W + 4194304,  i - 1048576);
  else if (i < 2883584) cvt4(gate_w, W + 7864320,  i - 1966080);
  else if (i < 3801088) cvt4(out_w,  W + 11534336, i - 2883584);
  else {
    const int j = i - 3801088;  // 0..767
    const float* src = j < 256 ? q_b : (j < 512 ? k_b : v_b);
    ((float4*)bqkv)[j] = ((const float4*)src)[j & 255];
  }
}

// ---------------------------------------------------------------- GEMM: C = A(bf16,MxK) * B(bf16,NxK)^T + bias
// 1D grid with XCD-aware bijective swizzle (nwg % 8 == 0 for all our launches).
// MODE 0: out bf16 = acc + bias
// MODE 1: out fp32 = acc + bias + f32 extra[idx]   (residual)
// MODE 3: out bf16 = silu(acc + bias) * bf16 extra[idx]
template <int MODE, int BM>
__global__ __launch_bounds__(256) void k_gemm(
    const u16* __restrict__ A, const u16* __restrict__ Bw,
    const float* __restrict__ bias, const void* extra,
    void* outp, int M, int N, int K, int nbx) {
  constexpr int ASEG = BM / 16;      // 1024B segments in A tile
  constexpr int NSEG = ASEG + 8;
  constexpr int WROWS = BM / 2;
  constexpr int MF = BM / 32;        // m-frags per wave
  __shared__ __align__(16) u16 As[BM * 32];
  __shared__ __align__(16) u16 Bs[128 * 32];
  const int tid = threadIdx.x, lane = tid & 63, wv_ = tid >> 6;
  const int lr = lane & 15, lg = lane >> 4;
  // XCD swizzle: XCD x owns a contiguous chunk of tiles (same-row tiles share A panel in L2)
  const int chunk = gridDim.x >> 3;
  const int sid = (blockIdx.x & 7) * chunk + (blockIdx.x >> 3);
  const int brow = (sid / nbx) * BM, bcol = (sid % nbx) * 128;
  const int wr = wv_ >> 1, wc = wv_ & 1;

  const f32x4 zz = {0.f, 0.f, 0.f, 0.f};
  f32x4 acc[MF][4];
#pragma unroll
  for (int m = 0; m < MF; m++)
#pragma unroll
    for (int n = 0; n < 4; n++) acc[m][n] = zz;

  for (int kt = 0; kt < K; kt += 32) {
#pragma unroll
    for (int i = 0; i < NSEG / 4; ++i) {
      const int seg = i * 4 + wv_;
      const int rsub = (seg < ASEG) ? seg : seg - ASEG;
      const int row = rsub * 16 + (lane >> 2), cs = lane & 3;
      if (seg < ASEG) {
        __builtin_amdgcn_global_load_lds(AS1(A + (size_t)(brow + row) * K + kt + cs * 8),
                                         AS3((char*)As + (size_t)seg * 1024), 16, 0, 0);
      } else {
        __builtin_amdgcn_global_load_lds(AS1(Bw + (size_t)(bcol + row) * K + kt + cs * 8),
                                         AS3((char*)Bs + (size_t)(seg - ASEG) * 1024), 16, 0, 0);
      }
    }
    __syncthreads();
    bf16x8 af[MF], bfr[4];
#pragma unroll
    for (int m = 0; m < MF; m++) af[m] = *(const bf16x8*)&As[(wr * WROWS + m * 16 + lr) * 32 + lg * 8];
#pragma unroll
    for (int n = 0; n < 4; n++) bfr[n] = *(const bf16x8*)&Bs[(wc * 64 + n * 16 + lr) * 32 + lg * 8];
#pragma unroll
    for (int m = 0; m < MF; m++)
#pragma unroll
      for (int n = 0; n < 4; n++)
        acc[m][n] = __builtin_amdgcn_mfma_f32_16x16x32_bf16(af[m], bfr[n], acc[m][n], 0, 0, 0);
    __syncthreads();
  }

  // epilogue: C layout col=lane&15, row=(lane>>4)*4+reg  [m89-verified]
#pragma unroll
  for (int m = 0; m < MF; m++) {
    const int row0 = brow + wr * WROWS + m * 16 + lg * 4;
#pragma unroll
    for (int n = 0; n < 4; n++) {
      const int col = bcol + wc * 64 + n * 16 + lr;
      const float bv = bias[col];
#pragma unroll
      for (int r = 0; r < 4; r++) {
        const size_t idx = (size_t)(row0 + r) * N + col;
        float v = acc[m][n][r] + bv;
        if (MODE == 0) {
          ((u16*)outp)[idx] = f2bf(v);
        } else if (MODE == 1) {
          ((float*)outp)[idx] = v + ((const float*)extra)[idx];
        } else {
          float g = v / (1.0f + __expf(-v));
          ((u16*)outp)[idx] = f2bf(g * bf2f(((const u16*)extra)[idx]));
        }
      }
    }
  }
}

// ---------------------------------------------------------------- flash attention (causal, paired q-blocks)
// grid: (16, B*H). Block p handles q-blocks {p, 31-p} over ONE shared double-buffered
// KV stream of 64-wide tiles (uniform 33 tile-computes/block). 4 waves, 16 q-rows each.
// Softmax: DPP row-max (no LDS shuffles); row-sum = 5th PV accumulator vs all-ones B.
__global__ __launch_bounds__(256) void k_attn(
    const u16* __restrict__ qkv, u16* __restrict__ attn_o) {
  __shared__ __align__(16) u16 Ks[2][64 * 64];    // [kv][d] byte = kv*128+d*2 ^ ((kv&7)<<4)
  __shared__ __align__(16) u16 Vt[2][64 * 64];    // [d][kv] byte = d*128+kv*2 ^ ((d&7)<<4)
  __shared__ __align__(16) u16 Pl[4][16 * 64];    // [q][k]  byte = q*128+k*2  ^ ((q&7)<<4)

  const int tid = threadIdx.x, lane = tid & 63, w = tid >> 6;
  const int lr = lane & 15, lg = lane >> 4;
  const int p = blockIdx.x, bh = blockIdx.y;
  const int b = bh >> 4, h = bh & 15;
  const int qbL = p, qbH = 31 - p;
  const size_t base = (size_t)b * kS;
  const f32x4 zz = {0.f, 0.f, 0.f, 0.f};
  bf16x8 vones;
#pragma unroll
  for (int j = 0; j < 8; j++) vones[j] = (short)0x3F80;  // bf16 1.0

  bf16x8 qfL[2], qfH[2];
#pragma unroll
  for (int ks = 0; ks < 2; ks++) {
    qfL[ks] = *(const bf16x8*)&qkv[(base + qbL * 64 + w * 16 + lr) * 3072 + h * 64 + ks * 32 + lg * 8];
    qfH[ks] = *(const bf16x8*)&qkv[(base + qbH * 64 + w * 16 + lr) * 3072 + h * 64 + ks * 32 + lg * 8];
  }

  f32x4 oL[4], oH[4], lL, lH;
  float mL[4], mH[4];
#pragma unroll
  for (int nb = 0; nb < 4; nb++) { oL[nb] = zz; oH[nb] = zz; }
  lL = zz; lH = zz;
#pragma unroll
  for (int r = 0; r < 4; r++) { mL[r] = -1e30f; mH[r] = -1e30f; }

  const int srow = tid >> 2, scol = (tid & 3) * 16;
  int4 kr0, kr1, vr0, vr1;
  auto issue = [&](int t) {
    const size_t rowb = (base + t * 64 + srow) * 3072 + h * 64;
    kr0 = *(const int4*)&qkv[rowb + 1024 + scol];
    kr1 = *(const int4*)&qkv[rowb + 1024 + scol + 8];
    vr0 = *(const int4*)&qkv[rowb + 2048 + scol];
    vr1 = *(const int4*)&qkv[rowb + 2048 + scol + 8];
  };
  auto commit = [&](int buf) {
    char* kb = (char*)&Ks[buf][0];
    char* vb = (char*)&Vt[buf][0];
    const int bo0 = (srow * 128 + scol * 2) ^ ((srow & 7) << 4);
    const int bo1 = (srow * 128 + scol * 2 + 16) ^ ((srow & 7) << 4);
    *(int4*)(kb + bo0) = kr0;
    *(int4*)(kb + bo1) = kr1;
    const u16* ve0 = (const u16*)&vr0;
    const u16* ve1 = (const u16*)&vr1;
#pragma unroll
    for (int j = 0; j < 8; j++) {
      const int d0 = scol + j;
      *(u16*)(vb + ((d0 * 128 + srow * 2) ^ ((d0 & 7) << 4))) = ve0[j];
      const int d1 = scol + 8 + j;
      *(u16*)(vb + ((d1 * 128 + srow * 2) ^ ((d1 & 7) << 4))) = ve1[j];
    }
  };

  auto compute = [&](const bf16x8* qf, f32x4* oacc, f32x4& lacc, float* mrow,
                     int qb, int t, bool masked, int buf) {
    const char* kbuf = (const char*)&Ks[buf][0];
    const char* vbuf = (const char*)&Vt[buf][0];
    f32x4 sc[4];
#pragma unroll
    for (int hn = 0; hn < 4; hn++) sc[hn] = zz;
#pragma unroll
    for (int hn = 0; hn < 4; hn++) {
      const int krow = hn * 16 + lr;
#pragma unroll
      for (int ks = 0; ks < 2; ks++) {
        const int bo = (krow * 128 + (ks * 32 + lg * 8) * 2) ^ ((krow & 7) << 4);
        bf16x8 kf = *(const bf16x8*)(kbuf + bo);
        sc[hn] = __builtin_amdgcn_mfma_f32_16x16x32_bf16(qf[ks], kf, sc[hn], 0, 0, 0);
      }
    }
    float alpha[4];
#pragma unroll
    for (int r = 0; r < 4; r++) {
      const int qa = qb * 64 + w * 16 + lg * 4 + r;
      float s0 = sc[0][r] * 0.125f, s1 = sc[1][r] * 0.125f;
      float s2 = sc[2][r] * 0.125f, s3 = sc[3][r] * 0.125f;
      if (masked) {
        if (t * 64 + lr > qa) s0 = -1e30f;
        if (t * 64 + 16 + lr > qa) s1 = -1e30f;
        if (t * 64 + 32 + lr > qa) s2 = -1e30f;
        if (t * 64 + 48 + lr > qa) s3 = -1e30f;
      }
      float mx = rowmax16(fmaxf(fmaxf(s0, s1), fmaxf(s2, s3)));
      const float mnew = fmaxf(mrow[r], mx);
      alpha[r] = __expf(mrow[r] - mnew);
      mrow[r] = mnew;
      sc[0][r] = __expf(s0 - mnew); sc[1][r] = __expf(s1 - mnew);
      sc[2][r] = __expf(s2 - mnew); sc[3][r] = __expf(s3 - mnew);
    }
#pragma unroll
    for (int nb = 0; nb < 4; nb++)
#pragma unroll
      for (int r = 0; r < 4; r++) oacc[nb][r] *= alpha[r];
#pragma unroll
    for (int r = 0; r < 4; r++) lacc[r] *= alpha[r];
    // P -> per-wave LDS (bf16), then PV (+ ones column for row-sum)
    char* pw = (char*)&Pl[w][0];
#pragma unroll
    for (int hn = 0; hn < 4; hn++)
#pragma unroll
      for (int r = 0; r < 4; r++) {
        const int prow = lg * 4 + r, pcol = hn * 16 + lr;
        *(u16*)(pw + ((prow * 128 + pcol * 2) ^ ((prow & 7) << 4))) = f2bf(sc[hn][r]);
      }
    bf16x8 pf[2];
#pragma unroll
    for (int ks = 0; ks < 2; ks++)
      pf[ks] = *(const bf16x8*)((const char*)pw + ((lr * 128 + (ks * 32 + lg * 8) * 2) ^ ((lr & 7) << 4)));
#pragma unroll
    for (int nb = 0; nb < 4; nb++) {
      const int vrow = nb * 16 + lr;
#pragma unroll
      for (int ks = 0; ks < 2; ks++) {
        const int bo = (vrow * 128 + (ks * 32 + lg * 8) * 2) ^ ((vrow & 7) << 4);
        bf16x8 vf = *(const bf16x8*)(vbuf + bo);
        oacc[nb] = __builtin_amdgcn_mfma_f32_16x16x32_bf16(pf[ks], vf, oacc[nb], 0, 0, 0);
      }
    }
#pragma unroll
    for (int ks = 0; ks < 2; ks++)
      lacc = __builtin_amdgcn_mfma_f32_16x16x32_bf16(pf[ks], vones, lacc, 0, 0, 0);
  };

  const int ntS = qbH + 1;  // staged tiles 0..qbH
  issue(0);
  commit(0);
  __syncthreads();
  for (int t = 0; t < ntS; ++t) {
    const bool haveNext = (t + 1 < ntS);
    const int buf = t & 1;
    if (haveNext) issue(t + 1);                 // loads in flight under compute (T14)
    compute(qfH, oH, lH, mH, qbH, t, t == qbH, buf);
    if (t <= qbL) compute(qfL, oL, lL, mL, qbL, t, t == qbL, buf);
    if (haveNext) commit(buf ^ 1);              // other buffer: no read hazard
    __syncthreads();                            // tile t+1 visible to all
  }

  auto epi = [&](f32x4* oacc, f32x4& lacc, int qb) {
#pragma unroll
    for (int nb = 0; nb < 4; nb++)
#pragma unroll
      for (int r = 0; r < 4; r++) {
        const int q = qb * 64 + w * 16 + lg * 4 + r;
        attn_o[(base + q) * kD + h * 64 + nb * 16 + lr] = f2bf(oacc[nb][r] / lacc[r]);
      }
  };
  epi(oH, lH, qbH);
  epi(oL, lL, qbL);
}

// ---------------------------------------------------------------- workspace layout (bytes)
constexpr size_t OFF_XR   = 0;                                   // fp32 [4096][1024]
constexpr size_t OFF_XN1  = OFF_XR  + (size_t)kN * kD * 4;       // bf16 [4096][1024]
constexpr size_t OFF_XN2  = OFF_XN1 + (size_t)kN * kD * 2;       // bf16 [4096][1024]
constexpr size_t OFF_W    = OFF_XN2 + (size_t)kN * kD * 2;       // bf16 weight arena
constexpr size_t OFF_BQKV = OFF_W + 15204352ull * 2;             // fp32 [3072]
constexpr size_t OFF_ACT  = OFF_BQKV + 3072 * 4;                 // activation arena

extern "C" void kernel_launch(void* const* d_in, const int* in_sizes, int n_in,
                              void* d_out, int out_size, void* d_ws, size_t ws_size,
                              hipStream_t stream) {
  const float* x     = (const float*)d_in[0];
  const float* pos   = (const float*)d_in[1];
  const float* n1w   = (const float*)d_in[2];
  const float* n2w   = (const float*)d_in[3];
  const float* q_w   = (const float*)d_in[4];
  const float* q_b   = (const float*)d_in[5];
  const float* k_w   = (const float*)d_in[6];
  const float* k_b   = (const float*)d_in[7];
  const float* v_w   = (const float*)d_in[8];
  const float* v_b   = (const float*)d_in[9];
  const float* o_w   = (const float*)d_in[10];
  const float* o_b   = (const float*)d_in[11];
  const float* in_w  = (const float*)d_in[12];
  const float* in_b  = (const float*)d_in[13];
  const float* gate_w= (const float*)d_in[14];
  const float* gate_b= (const float*)d_in[15];
  const float* out_w = (const float*)d_in[16];
  const float* out_b = (const float*)d_in[17];
  float* outf = (float*)d_out;
  char* ws = (char*)d_ws;

  float* xr   = (float*)(ws + OFF_XR);
  u16*   xn1  = (u16*)(ws + OFF_XN1);
  u16*   xn2  = (u16*)(ws + OFF_XN2);
  u16*   W    = (u16*)(ws + OFF_W);
  float* bqkv = (float*)(ws + OFF_BQKV);
  u16*   qkv  = (u16*)(ws + OFF_ACT);
  u16*   attn_o = (u16*)(ws + OFF_ACT + (size_t)kN * 3072 * 2);
  u16*   inoutb = (u16*)(ws + OFF_ACT);
  u16*   hb     = (u16*)(ws + OFF_ACT + (size_t)kN * kHID * 2);

  // weight arena offsets (u16)
  u16* Wq   = W + 0;
  u16* Wo   = W + 3145728;
  u16* Win  = W + 4194304;
  u16* Wg   = W + 7864320;
  u16* Wout = W + 11534336;

  // 1. pos add + RMSNorm1 ; fused weight conversion
  k_prep<<<kN, 256, 0, stream>>>(x, pos, n1w, xr, xn1);
  k_wprep<<<14851, 256, 0, stream>>>(q_w, k_w, v_w, o_w, in_w, gate_w, out_w,
                                     q_b, k_b, v_b, W, bqkv);

  // 2. QKV projection -> qkv bf16 [4096][3072]
  k_gemm<0, 128><<<768, 256, 0, stream>>>(xn1, Wq, bqkv, nullptr, qkv, kN, 3072, kD, 24);

  // 3. attention (paired causal blocks)
  k_attn<<<dim3(16, kB * kH), 256, 0, stream>>>(qkv, attn_o);

  // 4. O projection + residual -> d_out fp32
  k_gemm<1, 64><<<512, 256, 0, stream>>>(attn_o, Wo, o_b, xr, outf, kN, kD, kD, 8);

  // 5. RMSNorm2
  k_rms2<<<kN, 256, 0, stream>>>(outf, n2w, xn2);

  // 6. MLP: in GEMM (bf16 out), gate GEMM (silu*in -> bf16)
  k_gemm<0, 128><<<896, 256, 0, stream>>>(xn2, Win, in_b, nullptr, inoutb, kN, kHID, kD, 28);
  k_gemm<3, 128><<<896, 256, 0, stream>>>(xn2, Wg, gate_b, inoutb, hb, kN, kHID, kD, 28);

  // 7. MLP out GEMM + residual -> d_out
  k_gemm<1, 64><<<512, 256, 0, stream>>>(hb, Wout, out_b, outf, outf, kN, kD, kHID, 8);
}

// Round 5
// 489.389 us; speedup vs baseline: 1.0743x; 1.0743x over previous
//
#include <hip/hip_runtime.h>

typedef __attribute__((ext_vector_type(4))) float f32x4;
typedef __attribute__((ext_vector_type(8))) short bf16x8;
typedef unsigned short u16;

constexpr int kB = 2, kS = 2048, kD = 1024, kH = 16, kHD = 64, kHID = 3584;
constexpr int kN = kB * kS;  // 4096 tokens

__device__ __forceinline__ u16 f2bf(float f) {
  unsigned u = __float_as_uint(f);
  u = (u + 0x7FFFu + ((u >> 16) & 1u)) >> 16;
  return (u16)u;
}
__device__ __forceinline__ float bf2f(u16 v) {
  return __uint_as_float((unsigned)v << 16);
}

// 16-lane (DPP row) max reduction: row_ror 1,2,4,8 + fmax. VALU-only.
__device__ __forceinline__ float rowmax16(float v) {
  int t;
  t = __builtin_amdgcn_update_dpp(0, __float_as_int(v), 0x121, 0xf, 0xf, true);
  v = fmaxf(v, __int_as_float(t));
  t = __builtin_amdgcn_update_dpp(0, __float_as_int(v), 0x122, 0xf, 0xf, true);
  v = fmaxf(v, __int_as_float(t));
  t = __builtin_amdgcn_update_dpp(0, __float_as_int(v), 0x124, 0xf, 0xf, true);
  v = fmaxf(v, __int_as_float(t));
  t = __builtin_amdgcn_update_dpp(0, __float_as_int(v), 0x128, 0xf, 0xf, true);
  v = fmaxf(v, __int_as_float(t));
  return v;
}

#define AS1(p) ((const __attribute__((address_space(1))) void*)(p))
#define AS3(p) ((__attribute__((address_space(3))) void*)(p))

// ---------------------------------------------------------------- prep: x+pos, RMSNorm1
__global__ __launch_bounds__(256) void k_prep(
    const float* __restrict__ x, const float* __restrict__ pos,
    const float* __restrict__ w, float* __restrict__ xr, u16* __restrict__ xn) {
  const int n = blockIdx.x, t = threadIdx.x, s = n & (kS - 1);
  float4 a = ((const float4*)(x + (size_t)n * kD))[t];
  float4 p = ((const float4*)(pos + (size_t)s * kD))[t];
  a.x += p.x; a.y += p.y; a.z += p.z; a.w += p.w;
  ((float4*)(xr + (size_t)n * kD))[t] = a;
  float ss = a.x*a.x + a.y*a.y + a.z*a.z + a.w*a.w;
#pragma unroll
  for (int off = 1; off < 64; off <<= 1) ss += __shfl_xor(ss, off);
  __shared__ float red[4];
  if ((t & 63) == 0) red[t >> 6] = ss;
  __syncthreads();
  float rs = rsqrtf((red[0] + red[1] + red[2] + red[3]) * (1.0f / kD) + 1e-6f);
  float4 wv = ((const float4*)w)[t];
  ushort4 o;
  o.x = f2bf(a.x * rs * wv.x); o.y = f2bf(a.y * rs * wv.y);
  o.z = f2bf(a.z * rs * wv.z); o.w = f2bf(a.w * rs * wv.w);
  ((ushort4*)(xn + (size_t)n * kD))[t] = o;
}

// ---------------------------------------------------------------- RMSNorm2
__global__ __launch_bounds__(256) void k_rms2(
    const float* __restrict__ xin, const float* __restrict__ w, u16* __restrict__ xn) {
  const int n = blockIdx.x, t = threadIdx.x;
  float4 a = ((const float4*)(xin + (size_t)n * kD))[t];
  float ss = a.x*a.x + a.y*a.y + a.z*a.z + a.w*a.w;
#pragma unroll
  for (int off = 1; off < 64; off <<= 1) ss += __shfl_xor(ss, off);
  __shared__ float red[4];
  if ((t & 63) == 0) red[t >> 6] = ss;
  __syncthreads();
  float rs = rsqrtf((red[0] + red[1] + red[2] + red[3]) * (1.0f / kD) + 1e-6f);
  float4 wv = ((const float4*)w)[t];
  ushort4 o;
  o.x = f2bf(a.x * rs * wv.x); o.y = f2bf(a.y * rs * wv.y);
  o.z = f2bf(a.z * rs * wv.z); o.w = f2bf(a.w * rs * wv.w);
  ((ushort4*)(xn + (size_t)n * kD))[t] = o;
}

// ---------------------------------------------------------------- fused weight prep
__device__ __forceinline__ void cvt4(const float* __restrict__ s, u16* __restrict__ d, int j) {
  float4 v = ((const float4*)s)[j];
  ushort4 o;
  o.x = f2bf(v.x); o.y = f2bf(v.y); o.z = f2bf(v.z); o.w = f2bf(v.w);
  ((ushort4*)d)[j] = o;
}

__global__ __launch_bounds__(256) void k_wprep(
    const float* __restrict__ q_w, const float* __restrict__ k_w,
    const float* __restrict__ v_w, const float* __restrict__ o_w,
    const float* __restrict__ in_w, const float* __restrict__ gate_w,
    const float* __restrict__ out_w,
    const float* __restrict__ q_b, const float* __restrict__ k_b,
    const float* __restrict__ v_b,
    u16* __restrict__ W, float* __restrict__ bqkv) {
  const int i = blockIdx.x * 256 + threadIdx.x;
  if (i < 262144)       cvt4(q_w,    W + 0,        i);
  else if (i < 524288)  cvt4(k_w,    W + 1048576,  i - 262144);
  else if (i < 786432)  cvt4(v_w,    W + 2097152,  i - 524288);
  else if (i < 1048576) cvt4(o_w,    W + 3145728,  i - 786432);
  else if (i < 1966080) cvt4(in_w,   W + 4194304,  i - 1048576);
  else if (i < 2883584) cvt4(gate_w, W + 7864320,  i - 1966080);
  else if (i < 3801088) cvt4(out_w,  W + 11534336, i - 2883584);
  else {
    const int j = i - 3801088;  // 0..767
    const float* src = j < 256 ? q_b : (j < 512 ? k_b : v_b);
    ((float4*)bqkv)[j] = ((const float4*)src)[j & 255];
  }
}

// ---------------------------------------------------------------- GEMM: C = A(bf16,MxK) * B(bf16,NxK)^T + bias
// T3 minimum 2-phase: double LDS buffer, stage(t+1) issued BEFORE compute(t),
// single barrier per K-step (barrier drains the in-flight gload_lds).
// 1D grid with XCD-aware swizzle (nwg % 8 == 0 for all launches).
// MODE 0: out bf16 = acc + bias
// MODE 1: out fp32 = acc + bias + f32 extra[idx]   (residual)
// MODE 3: out bf16 = silu(acc + bias) * bf16 extra[idx]
template <int MODE, int BM>
__global__ __launch_bounds__(256) void k_gemm(
    const u16* __restrict__ A, const u16* __restrict__ Bw,
    const float* __restrict__ bias, const void* extra,
    void* outp, int M, int N, int K, int nbx) {
  constexpr int ASEG = BM / 16;      // 1024B segments in A tile
  constexpr int NSEG = ASEG + 8;
  constexpr int WROWS = BM / 2;
  constexpr int MF = BM / 32;        // m-frags per wave
  __shared__ __align__(16) u16 As[2][BM * 32];
  __shared__ __align__(16) u16 Bs[2][128 * 32];
  const int tid = threadIdx.x, lane = tid & 63, wv_ = tid >> 6;
  const int lr = lane & 15, lg = lane >> 4;
  const int chunk = gridDim.x >> 3;
  const int sid = (blockIdx.x & 7) * chunk + (blockIdx.x >> 3);
  const int brow = (sid / nbx) * BM, bcol = (sid % nbx) * 128;
  const int wr = wv_ >> 1, wc = wv_ & 1;

  const f32x4 zz = {0.f, 0.f, 0.f, 0.f};
  f32x4 acc[MF][4];
#pragma unroll
  for (int m = 0; m < MF; m++)
#pragma unroll
    for (int n = 0; n < 4; n++) acc[m][n] = zz;

  auto stage = [&](int kt, int buf) {
#pragma unroll
    for (int i = 0; i < NSEG / 4; ++i) {
      const int seg = i * 4 + wv_;
      const int rsub = (seg < ASEG) ? seg : seg - ASEG;
      const int row = rsub * 16 + (lane >> 2), cs = lane & 3;
      if (seg < ASEG) {
        __builtin_amdgcn_global_load_lds(AS1(A + (size_t)(brow + row) * K + kt + cs * 8),
                                         AS3((char*)&As[buf][0] + (size_t)seg * 1024), 16, 0, 0);
      } else {
        __builtin_amdgcn_global_load_lds(AS1(Bw + (size_t)(bcol + row) * K + kt + cs * 8),
                                         AS3((char*)&Bs[buf][0] + (size_t)(seg - ASEG) * 1024), 16, 0, 0);
      }
    }
  };

  stage(0, 0);
  __syncthreads();
  for (int kt = 0; kt < K; kt += 32) {
    const int cur = (kt >> 5) & 1;
    if (kt + 32 < K) stage(kt + 32, cur ^ 1);   // loads in flight under compute
    bf16x8 af[MF], bfr[4];
#pragma unroll
    for (int m = 0; m < MF; m++) af[m] = *(const bf16x8*)&As[cur][(wr * WROWS + m * 16 + lr) * 32 + lg * 8];
#pragma unroll
    for (int n = 0; n < 4; n++) bfr[n] = *(const bf16x8*)&Bs[cur][(wc * 64 + n * 16 + lr) * 32 + lg * 8];
#pragma unroll
    for (int m = 0; m < MF; m++)
#pragma unroll
      for (int n = 0; n < 4; n++)
        acc[m][n] = __builtin_amdgcn_mfma_f32_16x16x32_bf16(af[m], bfr[n], acc[m][n], 0, 0, 0);
    __syncthreads();   // reads of cur done; stage into cur^1 drained
  }

  // epilogue: C layout col=lane&15, row=(lane>>4)*4+reg  [m89-verified]
#pragma unroll
  for (int m = 0; m < MF; m++) {
    const int row0 = brow + wr * WROWS + m * 16 + lg * 4;
#pragma unroll
    for (int n = 0; n < 4; n++) {
      const int col = bcol + wc * 64 + n * 16 + lr;
      const float bv = bias[col];
#pragma unroll
      for (int r = 0; r < 4; r++) {
        const size_t idx = (size_t)(row0 + r) * N + col;
        float v = acc[m][n][r] + bv;
        if (MODE == 0) {
          ((u16*)outp)[idx] = f2bf(v);
        } else if (MODE == 1) {
          ((float*)outp)[idx] = v + ((const float*)extra)[idx];
        } else {
          float g = v / (1.0f + __expf(-v));
          ((u16*)outp)[idx] = f2bf(g * bf2f(((const u16*)extra)[idx]));
        }
      }
    }
  }
}

// ---------------------------------------------------------------- flash attention (causal, paired q-blocks, 8 waves)
// grid: (16, B*H), 512 threads = 8 waves. Block p: waves 0-3 own q-block 31-p,
// waves 4-7 own q-block p; both groups share one KV stream of 64-wide tiles.
// K staged via global_load_lds (pre-swizzled source), double-buffered.
// V^T reg-staged (issue early / commit late). Softmax: DPP row-max + ones-MFMA row-sum.
__global__ __launch_bounds__(512) void k_attn(
    const u16* __restrict__ qkv, u16* __restrict__ attn_o) {
  __shared__ __align__(16) u16 Ks[2][64 * 64];  // [kv][d] byte = kv*128+d*2 ^ ((kv&7)<<4)
  __shared__ __align__(16) u16 Vt[64 * 64];     // [d][kv] byte = d*128+kv*2 ^ ((d&7)<<4)
  __shared__ __align__(16) u16 Pl[8][16 * 64];  // per-wave [q][k] swizzled

  const int tid = threadIdx.x, lane = tid & 63, w = tid >> 6;
  const int g = w >> 2, wi = w & 3;
  const int lr = lane & 15, lg = lane >> 4;
  const int p = blockIdx.x, bh = blockIdx.y;
  const int b = bh >> 4, h = bh & 15;
  const int qb = g == 0 ? 31 - p : p;           // group H=0 gets high block
  const size_t base = (size_t)b * kS;
  const f32x4 zz = {0.f, 0.f, 0.f, 0.f};
  bf16x8 vones;
#pragma unroll
  for (int j = 0; j < 8; j++) vones[j] = (short)0x3F80;  // bf16 1.0

  bf16x8 qf[2];
#pragma unroll
  for (int ks = 0; ks < 2; ks++)
    qf[ks] = *(const bf16x8*)&qkv[(base + qb * 64 + wi * 16 + lr) * 3072 + h * 64 + ks * 32 + lg * 8];

  f32x4 oacc[4], lacc = zz;
  float mrow[4];
#pragma unroll
  for (int nb = 0; nb < 4; nb++) oacc[nb] = zz;
#pragma unroll
  for (int r = 0; r < 4; r++) mrow[r] = -1e30f;

  // K staging: wave w covers tile rows w*8..w*8+7; per-lane pre-swizzled source.
  const int kvloc = (w << 3) + (lane >> 3);                 // row in tile
  const int kchv = ((lane & 7) ^ (lane >> 3)) * 8;          // source d-offset (elems)
  auto issueK = [&](int t, int buf) {
    __builtin_amdgcn_global_load_lds(
        AS1(qkv + (base + t * 64 + kvloc) * 3072 + 1024 + h * 64 + kchv),
        AS3((char*)&Ks[buf][0] + w * 1024 + (size_t)lane * 16), 16, 0, 0);
  };
  // V staging: thread -> (row tid>>3, 8-elem chunk (tid&7)*8), reg-held int4.
  const int srow = tid >> 3, dc = (tid & 7) * 8;
  int4 vr;
  auto issueV = [&](int t) {
    vr = *(const int4*)&qkv[(base + t * 64 + srow) * 3072 + 2048 + h * 64 + dc];
  };
  auto commitV = [&]() {
    const u16* ve = (const u16*)&vr;
#pragma unroll
    for (int j = 0; j < 8; j++) {
      const int d = dc + j;
      *(u16*)((char*)Vt + ((d * 128 + srow * 2) ^ ((d & 7) << 4))) = ve[j];
    }
  };

  auto compute = [&](int t, int buf) {
    const char* kbuf = (const char*)&Ks[buf][0];
    const bool masked = (t == qb);
    f32x4 sc[4];
#pragma unroll
    for (int hn = 0; hn < 4; hn++) sc[hn] = zz;
#pragma unroll
    for (int hn = 0; hn < 4; hn++) {
      const int krow = hn * 16 + lr;
#pragma unroll
      for (int ks = 0; ks < 2; ks++) {
        const int bo = (krow * 128 + (ks * 32 + lg * 8) * 2) ^ ((krow & 7) << 4);
        bf16x8 kf = *(const bf16x8*)(kbuf + bo);
        sc[hn] = __builtin_amdgcn_mfma_f32_16x16x32_bf16(qf[ks], kf, sc[hn], 0, 0, 0);
      }
    }
    float alpha[4];
#pragma unroll
    for (int r = 0; r < 4; r++) {
      const int qa = qb * 64 + wi * 16 + lg * 4 + r;
      float s0 = sc[0][r] * 0.125f, s1 = sc[1][r] * 0.125f;
      float s2 = sc[2][r] * 0.125f, s3 = sc[3][r] * 0.125f;
      if (masked) {
        if (t * 64 + lr > qa) s0 = -1e30f;
        if (t * 64 + 16 + lr > qa) s1 = -1e30f;
        if (t * 64 + 32 + lr > qa) s2 = -1e30f;
        if (t * 64 + 48 + lr > qa) s3 = -1e30f;
      }
      float mx = rowmax16(fmaxf(fmaxf(s0, s1), fmaxf(s2, s3)));
      const float mnew = fmaxf(mrow[r], mx);
      alpha[r] = __expf(mrow[r] - mnew);
      mrow[r] = mnew;
      sc[0][r] = __expf(s0 - mnew); sc[1][r] = __expf(s1 - mnew);
      sc[2][r] = __expf(s2 - mnew); sc[3][r] = __expf(s3 - mnew);
    }
#pragma unroll
    for (int nb = 0; nb < 4; nb++)
#pragma unroll
      for (int r = 0; r < 4; r++) oacc[nb][r] *= alpha[r];
#pragma unroll
    for (int r = 0; r < 4; r++) lacc[r] *= alpha[r];
    char* pw = (char*)&Pl[w][0];
#pragma unroll
    for (int hn = 0; hn < 4; hn++)
#pragma unroll
      for (int r = 0; r < 4; r++) {
        const int prow = lg * 4 + r, pcol = hn * 16 + lr;
        *(u16*)(pw + ((prow * 128 + pcol * 2) ^ ((prow & 7) << 4))) = f2bf(sc[hn][r]);
      }
    bf16x8 pf[2];
#pragma unroll
    for (int ks = 0; ks < 2; ks++)
      pf[ks] = *(const bf16x8*)((const char*)pw + ((lr * 128 + (ks * 32 + lg * 8) * 2) ^ ((lr & 7) << 4)));
#pragma unroll
    for (int nb = 0; nb < 4; nb++) {
      const int vrow = nb * 16 + lr;
#pragma unroll
      for (int ks = 0; ks < 2; ks++) {
        const int bo = (vrow * 128 + (ks * 32 + lg * 8) * 2) ^ ((vrow & 7) << 4);
        bf16x8 vf = *(const bf16x8*)((const char*)Vt + bo);
        oacc[nb] = __builtin_amdgcn_mfma_f32_16x16x32_bf16(pf[ks], vf, oacc[nb], 0, 0, 0);
      }
    }
#pragma unroll
    for (int ks = 0; ks < 2; ks++)
      lacc = __builtin_amdgcn_mfma_f32_16x16x32_bf16(pf[ks], vones, lacc, 0, 0, 0);
  };

  const int nt = 32 - p;  // tiles 0..31-p (H range); L computes only t<=p
  issueV(0);
  issueK(0, 0);
  commitV();
  __syncthreads();
  for (int t = 0; t < nt; ++t) {
    const bool hn = (t + 1 < nt);
    if (hn) { issueV(t + 1); issueK(t + 1, (t + 1) & 1); }
    if (g == 0 || t <= p) compute(t, t & 1);
    __syncthreads();           // Vt reads done; K(t+1) DMA drained
    if (hn) commitV();
    __syncthreads();           // Vt(t+1) visible
  }

#pragma unroll
  for (int nb = 0; nb < 4; nb++)
#pragma unroll
    for (int r = 0; r < 4; r++) {
      const int q = qb * 64 + wi * 16 + lg * 4 + r;
      attn_o[(base + q) * kD + h * 64 + nb * 16 + lr] = f2bf(oacc[nb][r] / lacc[r]);
    }
}

// ---------------------------------------------------------------- workspace layout (bytes)
constexpr size_t OFF_XR   = 0;                                   // fp32 [4096][1024]
constexpr size_t OFF_XN1  = OFF_XR  + (size_t)kN * kD * 4;       // bf16 [4096][1024]
constexpr size_t OFF_XN2  = OFF_XN1 + (size_t)kN * kD * 2;       // bf16 [4096][1024]
constexpr size_t OFF_W    = OFF_XN2 + (size_t)kN * kD * 2;       // bf16 weight arena
constexpr size_t OFF_BQKV = OFF_W + 15204352ull * 2;             // fp32 [3072]
constexpr size_t OFF_ACT  = OFF_BQKV + 3072 * 4;                 // activation arena

extern "C" void kernel_launch(void* const* d_in, const int* in_sizes, int n_in,
                              void* d_out, int out_size, void* d_ws, size_t ws_size,
                              hipStream_t stream) {
  const float* x     = (const float*)d_in[0];
  const float* pos   = (const float*)d_in[1];
  const float* n1w   = (const float*)d_in[2];
  const float* n2w   = (const float*)d_in[3];
  const float* q_w   = (const float*)d_in[4];
  const float* q_b   = (const float*)d_in[5];
  const float* k_w   = (const float*)d_in[6];
  const float* k_b   = (const float*)d_in[7];
  const float* v_w   = (const float*)d_in[8];
  const float* v_b   = (const float*)d_in[9];
  const float* o_w   = (const float*)d_in[10];
  const float* o_b   = (const float*)d_in[11];
  const float* in_w  = (const float*)d_in[12];
  const float* in_b  = (const float*)d_in[13];
  const float* gate_w= (const float*)d_in[14];
  const float* gate_b= (const float*)d_in[15];
  const float* out_w = (const float*)d_in[16];
  const float* out_b = (const float*)d_in[17];
  float* outf = (float*)d_out;
  char* ws = (char*)d_ws;

  float* xr   = (float*)(ws + OFF_XR);
  u16*   xn1  = (u16*)(ws + OFF_XN1);
  u16*   xn2  = (u16*)(ws + OFF_XN2);
  u16*   W    = (u16*)(ws + OFF_W);
  float* bqkv = (float*)(ws + OFF_BQKV);
  u16*   qkv  = (u16*)(ws + OFF_ACT);
  u16*   attn_o = (u16*)(ws + OFF_ACT + (size_t)kN * 3072 * 2);
  u16*   inoutb = (u16*)(ws + OFF_ACT);
  u16*   hb     = (u16*)(ws + OFF_ACT + (size_t)kN * kHID * 2);

  // weight arena offsets (u16)
  u16* Wq   = W + 0;
  u16* Wo   = W + 3145728;
  u16* Win  = W + 4194304;
  u16* Wg   = W + 7864320;
  u16* Wout = W + 11534336;

  // 1. pos add + RMSNorm1 ; fused weight conversion
  k_prep<<<kN, 256, 0, stream>>>(x, pos, n1w, xr, xn1);
  k_wprep<<<14851, 256, 0, stream>>>(q_w, k_w, v_w, o_w, in_w, gate_w, out_w,
                                     q_b, k_b, v_b, W, bqkv);

  // 2. QKV projection -> qkv bf16 [4096][3072]
  k_gemm<0, 128><<<768, 256, 0, stream>>>(xn1, Wq, bqkv, nullptr, qkv, kN, 3072, kD, 24);

  // 3. attention (paired causal blocks, 8 waves)
  k_attn<<<dim3(16, kB * kH), 512, 0, stream>>>(qkv, attn_o);

  // 4. O projection + residual -> d_out fp32
  k_gemm<1, 64><<<512, 256, 0, stream>>>(attn_o, Wo, o_b, xr, outf, kN, kD, kD, 8);

  // 5. RMSNorm2
  k_rms2<<<kN, 256, 0, stream>>>(outf, n2w, xn2);

  // 6. MLP: in GEMM (bf16 out), gate GEMM (silu*in -> bf16)
  k_gemm<0, 128><<<896, 256, 0, stream>>>(xn2, Win, in_b, nullptr, inoutb, kN, kHID, kD, 28);
  k_gemm<3, 128><<<896, 256, 0, stream>>>(xn2, Wg, gate_b, inoutb, hb, kN, kHID, kD, 28);

  // 7. MLP out GEMM + residual -> d_out
  k_gemm<1, 64><<<512, 256, 0, stream>>>(hb, Wout, out_b, outf, outf, kN, kD, kHID, 8);
}